// Round 18
// baseline (87.023 us; speedup 1.0000x reference)
//
#include <hip/hip_runtime.h>
#include <math.h>

// AttnSum3d via pure-bf16 MFMA + symmetry + bound-shifted softmax.
//   X = x*mask scaled by sqrt(log2 e); H = bf16(X) (L x 128 bf16).
//   S' = H H^T = S*log2(e) (symmetric). Cauchy-Schwarz bound C_m = n_m*Nmax
//   (norms of ROUNDED rows) >= column max; every term 2^(S'-C_m) <= 1 --
//   safe in f32, no max tracking in the GEMM passes.
//   csum[m] = sum_l 2^(S'[l,m]-C_m);  Q_m = -C_m - log2(csum_m);
//   r[l] = sum_m 2^(S'[l,m]+Q_m);  out[b,0,d] = (1/L) sum_l X[l,d] r[l];
//   attn_mean = 1/L exactly.
// R18: ordinary-launch fusion of the small kernels (cooperative launch is
// dead in this harness -- R15/R16 silent non-launch):
//   - k_nmax folded into k_esum prologue (each block scans nsq[b] redundantly,
//     ~4MB L2 total; duplicate identical nmaxf[b] stores are benign). No
//     atomics (R8 lesson).
//   - k_comb folded into k_r (Qr_s[128]/block prologue; Qc_s[128]/tile
//     computed by tid<128 between Bt stage-issue and its barrier, hidden
//     under staging latency). rp UN-ALIASED from pcs (k_r reads pcs while
//     writing rp -- alias would race).
// Launches 7 -> 5.  GEMM structure identical to R14/R17 (66.1us passing):
// strip decomposition (row-block ib owns wrapped distances d; hf=0: 0..3,
// hf=1: 4..7 +8 if ib<8); 512 half-strip blocks, XCD-swizzled (2 batches
// per XCD); 8-wave blocks, wave grid 2x4, per-wave tile 64x32, acc[4][2];
// At persistent in LDS + Bt per tile, 2 barriers/tile; barrier-free
// per-wave epilogues (NSLOT=24 collision-free global slots).

constexpr int NB = 16, NL = 2048, ND = 128;
constexpr int ROWS_US = 128;  // ushorts per H row (K = 128 bf16)
constexpr int NSLOT = 24;     // 0..7 row-dir (4*hf+wc); 8..23 col-dir (8+2*(d-1)+wr)

typedef __attribute__((ext_vector_type(8))) short short8;
typedef __attribute__((ext_vector_type(4))) float f32x4;

#define EXP2(x) __builtin_amdgcn_exp2f(x)

__device__ __forceinline__ unsigned short f2bf(float f) {
  unsigned u = __builtin_bit_cast(unsigned, f);
  u += 0x7FFFu + ((u >> 16) & 1u);
  return (unsigned short)(u >> 16);
}
__device__ __forceinline__ float bf2f(unsigned short h) {
  unsigned u = ((unsigned)h) << 16;
  return __builtin_bit_cast(float, u);
}

__device__ __forceinline__ void stage16(const unsigned short* g, unsigned short* l) {
  __builtin_amdgcn_global_load_lds(
      (const __attribute__((address_space(1))) unsigned int*)g,
      (__attribute__((address_space(3))) unsigned int*)l, 16, 0, 0);
}

// prep: scale by sqrt(log2 e)*mask, round to bf16, swizzled store, row norm^2
// of the ROUNDED values; also fills the constant attn_mean output (1/L).
__global__ __launch_bounds__(256) void k_prep(const float* __restrict__ x,
                                              const float* __restrict__ mask,
                                              unsigned short* __restrict__ Y,
                                              float* __restrict__ nsq,
                                              float* __restrict__ am) {
  const int gid = blockIdx.x * 256 + threadIdx.x;  // one float4 (4 d-elems)
  if (gid < NB * NL) am[gid] = 1.0f / NL;  // attn_mean == 1/L exactly
  const int row = gid >> 5;
  const int dq = gid & 31;
  const float4 v = reinterpret_cast<const float4*>(x)[gid];
  const float m = mask[row] * 1.2011224087864498f;  // sqrt(log2 e)
  const unsigned short h0 = f2bf(v.x * m), h1 = f2bf(v.y * m),
                       h2 = f2bf(v.z * m), h3 = f2bf(v.w * m);
  const float g0 = bf2f(h0), g1 = bf2f(h1), g2 = bf2f(h2), g3 = bf2f(h3);
  unsigned short* Yr = Y + (size_t)row * ROWS_US;
  const int sx = dq >> 1, half8 = (dq & 1) * 4;
  const int pos = sx ^ (row & 15);  // XOR within the 16 16B-slots
  *reinterpret_cast<ushort4*>(Yr + pos * 8 + half8) = make_ushort4(h0, h1, h2, h3);
  float ss = g0 * g0 + g1 * g1 + g2 * g2 + g3 * g3;
#pragma unroll
  for (int mk = 1; mk < 32; mk <<= 1) ss += __shfl_xor(ss, mk);
  if (dq == 0) nsq[row] = ss;
}

// Block decode: xcd = sid&7 owns 2 batches; 32 half-strips per batch.
// 512 threads: wave grid 2x4 (wr rows, wc cols).
#define STRIP_DECODE()                                     \
  const int sid = blockIdx.x;                              \
  const int idx = sid >> 3;                                \
  const int b = ((sid & 7) << 1) | (idx >> 5);             \
  const int strip = idx & 31;                              \
  const int ib = strip >> 1, hf = strip & 1;               \
  const int d0 = hf * 4;                                   \
  const int nt = (hf == 0) ? 4 : ((ib < 8) ? 5 : 4);       \
  const int row0 = ib * 128;                               \
  const int tid = threadIdx.x;                             \
  const int lane = tid & 63, wave = tid >> 6;              \
  const int wr = wave >> 2, wc = wave & 3;                 \
  const int lhi = lane >> 4, llo = lane & 15;

// Stage a full 128-row tile (32 KB) with 512 threads (4 iters).
#define STAGE_T(dst, Yb, r0)                                                \
  _Pragma("unroll") for (int it = 0; it < 4; ++it) {                        \
    const int idx2 = tid + 512 * it;                                        \
    const int r = idx2 >> 4, s = idx2 & 15;                                 \
    stage16((Yb) + (size_t)((r0) + r) * ROWS_US + s * 8, (dst) + idx2 * 8); \
  }

// Per-tile MFMA: wave tile 64x32 -> acc[4][2] (32 f32/lane).
#define TILE_MFMA(Atp, Btp)                                                  \
  f32x4 acc[4][2];                                                           \
  _Pragma("unroll") for (int rs = 0; rs < 4; ++rs)                           \
      _Pragma("unroll") for (int cs = 0; cs < 2; ++cs)                       \
          acc[rs][cs] = f32x4{0.f, 0.f, 0.f, 0.f};                           \
  _Pragma("unroll") for (int t4 = 0; t4 < 4; ++t4) {                         \
    const int sl = 4 * t4 + lhi;                                             \
    short8 af[4], bf[2];                                                     \
    _Pragma("unroll") for (int qq = 0; qq < 4; ++qq) {                       \
      const int ra = 64 * wr + 16 * qq + llo;                                \
      af[qq] = *(const short8*)((Atp) + ra * 128 + ((sl ^ (ra & 15)) << 3)); \
    }                                                                        \
    _Pragma("unroll") for (int cs = 0; cs < 2; ++cs) {                       \
      const int rb = 32 * wc + 16 * cs + llo;                                \
      bf[cs] = *(const short8*)((Btp) + rb * 128 + ((sl ^ (rb & 15)) << 3)); \
    }                                                                        \
    _Pragma("unroll") for (int rs = 0; rs < 4; ++rs)                         \
        _Pragma("unroll") for (int cs = 0; cs < 2; ++cs)                     \
            acc[rs][cs] = __builtin_amdgcn_mfma_f32_16x16x32_bf16(           \
                af[rs], bf[cs], acc[rs][cs], 0, 0, 0);                       \
  }

// ---- pass 1: csum partials; per-block Nmax fused in prologue ----
__global__ __launch_bounds__(512, 4) void k_esum(const unsigned short* __restrict__ Y,
                                                 const float* __restrict__ nsq,
                                                 float* __restrict__ nmaxf,
                                                 float* __restrict__ pcs) {
  __shared__ alignas(128) char lds[65600];
  unsigned short* At = (unsigned short*)lds;            // 32 KB persistent
  unsigned short* Bt = (unsigned short*)(lds + 32768);  // 32 KB per-tile
  float* red8 = (float*)(lds + 65536);                  // 8-wave nmax reduce
  STRIP_DECODE()
  const unsigned short* Yb = Y + (size_t)b * NL * ROWS_US;

  STAGE_T(At, Yb, row0)

  // per-block Nmax over nsq[b] (redundant per block; no atomics -- R8 lesson)
  float mx_ = 0.f;
  for (int i = tid; i < NL; i += 512) mx_ = fmaxf(mx_, nsq[b * NL + i]);
#pragma unroll
  for (int mk = 1; mk < 64; mk <<= 1) mx_ = fmaxf(mx_, __shfl_xor(mx_, mk));
  if (lane == 0) red8[wave] = mx_;
  __syncthreads();
  float Nmx = red8[0];
#pragma unroll
  for (int k = 1; k < 8; ++k) Nmx = fmaxf(Nmx, red8[k]);
  if (tid == 0) nmaxf[b] = Nmx;  // duplicate identical stores across blocks: benign

  float Cr[16];
#pragma unroll
  for (int rs = 0; rs < 4; ++rs)
#pragma unroll
    for (int rg = 0; rg < 4; ++rg)
      Cr[rs * 4 + rg] = sqrtf(nsq[b * NL + row0 + 64 * wr + 16 * rs + 4 * lhi + rg] * Nmx);

  float racc[16];
#pragma unroll
  for (int i = 0; i < 16; ++i) racc[i] = 0.f;

  for (int dt = 0; dt < nt; ++dt) {
    const int d = d0 + dt;
    const int col0 = ((ib + d) & 15) * 128;
    __syncthreads();  // prev Bt reads done (At stage drained at nmax barrier)
    STAGE_T(Bt, Yb, col0)
    float Cc[2];
#pragma unroll
    for (int cs = 0; cs < 2; ++cs)
      Cc[cs] = sqrtf(nsq[b * NL + col0 + 32 * wc + 16 * cs + llo] * Nmx);
    __syncthreads();  // Bt ready
    TILE_MFMA(At, Bt)
    // row-direction: csum[row0+i] partial over this wave's 32 cols
#pragma unroll
    for (int rs = 0; rs < 4; ++rs)
#pragma unroll
      for (int rg = 0; rg < 4; ++rg)
        racc[rs * 4 + rg] += EXP2(acc[rs][0][rg] - Cr[rs * 4 + rg]) +
                             EXP2(acc[rs][1][rg] - Cr[rs * 4 + rg]);
    // col-direction: per-wave partial straight to global (no LDS, no barrier)
    if (d != 0) {
      float* dst = pcs + ((size_t)(b * NSLOT + 8 + 2 * (d - 1) + wr)) * NL + col0;
#pragma unroll
      for (int cs = 0; cs < 2; ++cs) {
        float u = 0.f;
#pragma unroll
        for (int rs = 0; rs < 4; ++rs)
#pragma unroll
          for (int rg = 0; rg < 4; ++rg) u += EXP2(acc[rs][cs][rg] - Cc[cs]);
        u += __shfl_xor(u, 16);
        u += __shfl_xor(u, 32);
        if (lhi == 0) dst[32 * wc + 16 * cs + llo] = u;
      }
    }
  }
  // strip-end row-direction: llo-reduce; slot 4*hf+wc, rows disjoint by wr
#pragma unroll
  for (int i = 0; i < 16; ++i) {
    float s = racc[i];
#pragma unroll
    for (int mk = 1; mk < 16; mk <<= 1) s += __shfl_xor(s, mk);
    racc[i] = s;
  }
  if (llo == 0) {
    float* dst = pcs + ((size_t)(b * NSLOT + 4 * hf + wc)) * NL + row0;
#pragma unroll
    for (int rs = 0; rs < 4; ++rs)
#pragma unroll
      for (int rg = 0; rg < 4; ++rg)
        dst[64 * wr + 16 * rs + 4 * lhi + rg] = racc[rs * 4 + rg];
  }
}

// ---- pass 2: r partials; Q computed on the fly from pcs (k_comb fused) ----
__global__ __launch_bounds__(512, 4) void k_r(const unsigned short* __restrict__ Y,
                                              const float* __restrict__ nsq,
                                              const float* __restrict__ nmaxf,
                                              const float* __restrict__ pcs,
                                              float* __restrict__ rp) {
  __shared__ alignas(128) char lds[66560];
  unsigned short* At = (unsigned short*)lds;
  unsigned short* Bt = (unsigned short*)(lds + 32768);
  float* Qr_s = (float*)(lds + 65536);  // [128]
  float* Qc_s = (float*)(lds + 66048);  // [128]
  STRIP_DECODE()
  const unsigned short* Yb = Y + (size_t)b * NL * ROWS_US;
  const float Nmx = nmaxf[b];

  STAGE_T(At, Yb, row0)

  // Q for this block's 128 rows (pcs complete at kernel entry)
  if (tid < 128) {
    const int row = row0 + tid;
    float s = 0.f;
#pragma unroll
    for (int c = 0; c < NSLOT; ++c) {
      if (c >= 22 && ib < 8) continue;  // d=8 col-dir slots only for owners >= 8
      s += pcs[((size_t)(b * NSLOT + c)) * NL + row];
    }
    Qr_s[tid] = -sqrtf(nsq[b * NL + row] * Nmx) - __log2f(s);
  }
  __syncthreads();  // Qr_s ready (also drains At stage)

  float Qr[16];
#pragma unroll
  for (int rs = 0; rs < 4; ++rs)
#pragma unroll
    for (int rg = 0; rg < 4; ++rg)
      Qr[rs * 4 + rg] = Qr_s[64 * wr + 16 * rs + 4 * lhi + rg];

  float racc[16];
#pragma unroll
  for (int i = 0; i < 16; ++i) racc[i] = 0.f;

  for (int dt = 0; dt < nt; ++dt) {
    const int d = d0 + dt;
    const int jb = (ib + d) & 15;
    const int col0 = jb * 128;
    __syncthreads();  // prev Bt reads + prev Qc_s reads done
    STAGE_T(Bt, Yb, col0)
    // Q for this tile's 128 cols, hidden under Bt staging
    if (tid < 128) {
      const int col = col0 + tid;
      float s = 0.f;
#pragma unroll
      for (int c = 0; c < NSLOT; ++c) {
        if (c >= 22 && jb < 8) continue;
        s += pcs[((size_t)(b * NSLOT + c)) * NL + col];
      }
      Qc_s[tid] = -sqrtf(nsq[b * NL + col] * Nmx) - __log2f(s);
    }
    __syncthreads();  // Bt + Qc_s ready
    float Qc[2];
#pragma unroll
    for (int cs = 0; cs < 2; ++cs) Qc[cs] = Qc_s[32 * wc + 16 * cs + llo];
    TILE_MFMA(At, Bt)
    // row-direction: r[row0+i] += sum_m 2^(S' + Q_m) over wave's 32 cols
#pragma unroll
    for (int rs = 0; rs < 4; ++rs)
#pragma unroll
      for (int rg = 0; rg < 4; ++rg)
        racc[rs * 4 + rg] += EXP2(acc[rs][0][rg] + Qc[0]) +
                             EXP2(acc[rs][1][rg] + Qc[1]);
    // col-direction: per-wave partial straight to global
    if (d != 0) {
      float* dst = rp + ((size_t)(b * NSLOT + 8 + 2 * (d - 1) + wr)) * NL + col0;
#pragma unroll
      for (int cs = 0; cs < 2; ++cs) {
        float u = 0.f;
#pragma unroll
        for (int rs = 0; rs < 4; ++rs)
#pragma unroll
          for (int rg = 0; rg < 4; ++rg) u += EXP2(acc[rs][cs][rg] + Qr[rs * 4 + rg]);
        u += __shfl_xor(u, 16);
        u += __shfl_xor(u, 32);
        if (lhi == 0) dst[32 * wc + 16 * cs + llo] = u;
      }
    }
  }
#pragma unroll
  for (int i = 0; i < 16; ++i) {
    float s = racc[i];
#pragma unroll
    for (int mk = 1; mk < 16; mk <<= 1) s += __shfl_xor(s, mk);
    racc[i] = s;
  }
  if (llo == 0) {
    float* dst = rp + ((size_t)(b * NSLOT + 4 * hf + wc)) * NL + row0;
#pragma unroll
    for (int rs = 0; rs < 4; ++rs)
#pragma unroll
      for (int rg = 0; rg < 4; ++rg)
        dst[64 * wr + 16 * rs + 4 * lhi + rg] = racc[rs * 4 + rg];
  }
}

// ---- pass 3a: per-(b,seg) partial of sum_l w[l]*x[l,:] ----
__global__ __launch_bounds__(256) void k_outp(const float* __restrict__ x,
                                              const float* __restrict__ mask,
                                              const float* __restrict__ rp,
                                              float* __restrict__ partial) {
  const int b = blockIdx.y;
  const int seg = blockIdx.x;  // 16 segments of 128 rows; owner block == seg
  const int tid = threadIdx.x;
  const int l0 = seg * 128;
  __shared__ float w_s[128];
  __shared__ float4 red[8][32];
  if (tid < 128) {
    float s = 0.f;
#pragma unroll
    for (int c = 0; c < NSLOT; ++c) {
      if (c >= 22 && seg < 8) continue;
      s += rp[((size_t)(b * NSLOT + c)) * NL + l0 + tid];
    }
    w_s[tid] = s * mask[b * NL + l0 + tid];
  }
  __syncthreads();
  const int dq = tid & 31;
  const int rg = tid >> 5;
  float4 acc = make_float4(0.f, 0.f, 0.f, 0.f);
#pragma unroll 4
  for (int i = 0; i < 16; ++i) {
    const int l = 8 * i + rg;
    const float w = w_s[l];
    const float4 v = *reinterpret_cast<const float4*>(x + ((size_t)b * NL + l0 + l) * ND + 4 * dq);
    acc.x += w * v.x; acc.y += w * v.y; acc.z += w * v.z; acc.w += w * v.w;
  }
  red[rg][dq] = acc;
  __syncthreads();
  if (rg == 0) {
    float4 s = acc;
#pragma unroll
    for (int k = 1; k < 8; ++k) {
      const float4 t = red[k][dq];
      s.x += t.x; s.y += t.y; s.z += t.z; s.w += t.w;
    }
    *reinterpret_cast<float4*>(partial + ((size_t)(b * 16 + seg)) * ND + 4 * dq) = s;
  }
}

// ---- pass 3b: finalize out (attn_mean already filled by k_prep) ----
__global__ __launch_bounds__(1024) void k_fin(const float* __restrict__ partial,
                                              float* __restrict__ out) {
  const int gid = blockIdx.x * 1024 + threadIdx.x;  // 0..2047
  const int b = gid >> 7, d = gid & (ND - 1);
  float s = 0.f;
#pragma unroll
  for (int k = 0; k < 16; ++k) s += partial[(size_t)(b * 16 + k) * ND + d];
  out[gid] = s * (1.0f / NL);
}

extern "C" void kernel_launch(void* const* d_in, const int* in_sizes, int n_in,
                              void* d_out, int out_size, void* d_ws, size_t ws_size,
                              hipStream_t stream) {
  const float* x = (const float*)d_in[0];     // [16,2048,128] f32
  const float* mask = (const float*)d_in[1];  // [16,2048] f32
  float* out = (float*)d_out;

  unsigned short* Y = (unsigned short*)d_ws;                   // 8.4 MB
  float* nsq = (float*)(Y + (size_t)NB * NL * ROWS_US);        // [NB*NL]
  float* nmaxf = nsq + NB * NL;                                // [NB] (+pad)
  float* pcs = nmaxf + 16;                                     // [NB*NSLOT*NL] = 3 MB
  float* rp = pcs + (size_t)NB * NSLOT * NL;                   // [NB*NSLOT*NL] = 3 MB (NOT aliased: k_r reads pcs while writing rp)
  float* partial = rp + (size_t)NB * NSLOT * NL;               // [NB*16*ND]

  k_prep<<<dim3(NB * NL * ND / 4 / 256), 256, 0, stream>>>(x, mask, Y, nsq,
                                                           out + NB * ND);
  k_esum<<<dim3(512), 512, 0, stream>>>(Y, nsq, nmaxf, pcs);
  k_r<<<dim3(512), 512, 0, stream>>>(Y, nsq, nmaxf, pcs, rp);
  k_outp<<<dim3(16, NB), 256, 0, stream>>>(x, mask, rp, partial);
  k_fin<<<2, 1024, 0, stream>>>(partial, out);
}

// Round 19
// 63.375 us; speedup vs baseline: 1.3731x; 1.3731x over previous
//
#include <hip/hip_runtime.h>
#include <math.h>

// AttnSum3d via pure-bf16 MFMA + symmetry + bound-shifted softmax.
//   X = x*mask scaled by sqrt(log2 e); H = bf16(X) (L x 128 bf16).
//   S' = H H^T = S*log2(e) (symmetric). Cauchy-Schwarz bound C_m = n_m*Nmax
//   (norms of ROUNDED rows) >= column max; every term 2^(S'-C_m) <= 1 --
//   safe in f32, no max tracking in the GEMM passes.
//   csum[m] = sum_l 2^(S'[l,m]-C_m);  Q_m = -C_m - log2(csum_m);
//   r[l] = sum_m 2^(S'[l,m]+Q_m);  out[b,0,d] = (1/L) sum_l X[l,d] r[l];
//   attn_mean = 1/L exactly.
// R19 = R17 (66.08us passing) + ONLY the safe half of R18's fusion:
//   - k_nmax folded into k_esum PROLOGUE (scan + wave/LDS reduce, outside the
//     main loop -> no register-pressure change; duplicate identical nmaxf[b]
//     stores benign; no atomics -- R8 lesson). Launches 7 -> 6.
//   - k_comb kept separate: R18 fused Q-from-pcs into k_r's MAIN LOOP (24-slot
//     unrolled pcs reduce per tile) -> VGPR capped at 64, 45MB scratch spill,
//     k_r 15->50us. In-loop multi-pointer fusions spill; prologue fusions OK.
// Structure (R14): strip decomposition (row-block ib owns wrapped distances
// d; hf=0: 0..3, hf=1: 4..7 +8 if ib<8); 512 half-strip blocks, XCD-swizzled
// (2 batches/XCD); 8-wave blocks, wave grid 2x4, per-wave tile 64x32,
// acc[4][2]; At persistent in LDS + Bt per tile, 2 barriers/tile;
// barrier-free per-wave epilogues (NSLOT=24 collision-free global slots).

constexpr int NB = 16, NL = 2048, ND = 128;
constexpr int ROWS_US = 128;  // ushorts per H row (K = 128 bf16)
constexpr int NSLOT = 24;     // 0..7 row-dir (4*hf+wc); 8..23 col-dir (8+2*(d-1)+wr)

typedef __attribute__((ext_vector_type(8))) short short8;
typedef __attribute__((ext_vector_type(4))) float f32x4;

#define EXP2(x) __builtin_amdgcn_exp2f(x)

__device__ __forceinline__ unsigned short f2bf(float f) {
  unsigned u = __builtin_bit_cast(unsigned, f);
  u += 0x7FFFu + ((u >> 16) & 1u);
  return (unsigned short)(u >> 16);
}
__device__ __forceinline__ float bf2f(unsigned short h) {
  unsigned u = ((unsigned)h) << 16;
  return __builtin_bit_cast(float, u);
}

__device__ __forceinline__ void stage16(const unsigned short* g, unsigned short* l) {
  __builtin_amdgcn_global_load_lds(
      (const __attribute__((address_space(1))) unsigned int*)g,
      (__attribute__((address_space(3))) unsigned int*)l, 16, 0, 0);
}

// prep: scale by sqrt(log2 e)*mask, round to bf16, swizzled store, row norm^2
// of the ROUNDED values; also fills the constant attn_mean output (1/L).
__global__ __launch_bounds__(256) void k_prep(const float* __restrict__ x,
                                              const float* __restrict__ mask,
                                              unsigned short* __restrict__ Y,
                                              float* __restrict__ nsq,
                                              float* __restrict__ am) {
  const int gid = blockIdx.x * 256 + threadIdx.x;  // one float4 (4 d-elems)
  if (gid < NB * NL) am[gid] = 1.0f / NL;  // attn_mean == 1/L exactly
  const int row = gid >> 5;
  const int dq = gid & 31;
  const float4 v = reinterpret_cast<const float4*>(x)[gid];
  const float m = mask[row] * 1.2011224087864498f;  // sqrt(log2 e)
  const unsigned short h0 = f2bf(v.x * m), h1 = f2bf(v.y * m),
                       h2 = f2bf(v.z * m), h3 = f2bf(v.w * m);
  const float g0 = bf2f(h0), g1 = bf2f(h1), g2 = bf2f(h2), g3 = bf2f(h3);
  unsigned short* Yr = Y + (size_t)row * ROWS_US;
  const int sx = dq >> 1, half8 = (dq & 1) * 4;
  const int pos = sx ^ (row & 15);  // XOR within the 16 16B-slots
  *reinterpret_cast<ushort4*>(Yr + pos * 8 + half8) = make_ushort4(h0, h1, h2, h3);
  float ss = g0 * g0 + g1 * g1 + g2 * g2 + g3 * g3;
#pragma unroll
  for (int mk = 1; mk < 32; mk <<= 1) ss += __shfl_xor(ss, mk);
  if (dq == 0) nsq[row] = ss;
}

// Block decode: xcd = sid&7 owns 2 batches; 32 half-strips per batch.
// 512 threads: wave grid 2x4 (wr rows, wc cols).
#define STRIP_DECODE()                                     \
  const int sid = blockIdx.x;                              \
  const int idx = sid >> 3;                                \
  const int b = ((sid & 7) << 1) | (idx >> 5);             \
  const int strip = idx & 31;                              \
  const int ib = strip >> 1, hf = strip & 1;               \
  const int d0 = hf * 4;                                   \
  const int nt = (hf == 0) ? 4 : ((ib < 8) ? 5 : 4);       \
  const int row0 = ib * 128;                               \
  const int tid = threadIdx.x;                             \
  const int lane = tid & 63, wave = tid >> 6;              \
  const int wr = wave >> 2, wc = wave & 3;                 \
  const int lhi = lane >> 4, llo = lane & 15;

// Stage a full 128-row tile (32 KB) with 512 threads (4 iters).
#define STAGE_T(dst, Yb, r0)                                                \
  _Pragma("unroll") for (int it = 0; it < 4; ++it) {                        \
    const int idx2 = tid + 512 * it;                                        \
    const int r = idx2 >> 4, s = idx2 & 15;                                 \
    stage16((Yb) + (size_t)((r0) + r) * ROWS_US + s * 8, (dst) + idx2 * 8); \
  }

// Per-tile MFMA: wave tile 64x32 -> acc[4][2] (32 f32/lane).
#define TILE_MFMA(Atp, Btp)                                                  \
  f32x4 acc[4][2];                                                           \
  _Pragma("unroll") for (int rs = 0; rs < 4; ++rs)                           \
      _Pragma("unroll") for (int cs = 0; cs < 2; ++cs)                       \
          acc[rs][cs] = f32x4{0.f, 0.f, 0.f, 0.f};                           \
  _Pragma("unroll") for (int t4 = 0; t4 < 4; ++t4) {                         \
    const int sl = 4 * t4 + lhi;                                             \
    short8 af[4], bf[2];                                                     \
    _Pragma("unroll") for (int qq = 0; qq < 4; ++qq) {                       \
      const int ra = 64 * wr + 16 * qq + llo;                                \
      af[qq] = *(const short8*)((Atp) + ra * 128 + ((sl ^ (ra & 15)) << 3)); \
    }                                                                        \
    _Pragma("unroll") for (int cs = 0; cs < 2; ++cs) {                       \
      const int rb = 32 * wc + 16 * cs + llo;                                \
      bf[cs] = *(const short8*)((Btp) + rb * 128 + ((sl ^ (rb & 15)) << 3)); \
    }                                                                        \
    _Pragma("unroll") for (int rs = 0; rs < 4; ++rs)                         \
        _Pragma("unroll") for (int cs = 0; cs < 2; ++cs)                     \
            acc[rs][cs] = __builtin_amdgcn_mfma_f32_16x16x32_bf16(           \
                af[rs], bf[cs], acc[rs][cs], 0, 0, 0);                       \
  }

// ---- pass 1: csum partials; per-block Nmax fused in PROLOGUE ----
__global__ __launch_bounds__(512, 4) void k_esum(const unsigned short* __restrict__ Y,
                                                 const float* __restrict__ nsq,
                                                 float* __restrict__ nmaxf,
                                                 float* __restrict__ pcs) {
  __shared__ alignas(128) char lds[65600];
  unsigned short* At = (unsigned short*)lds;            // 32 KB persistent
  unsigned short* Bt = (unsigned short*)(lds + 32768);  // 32 KB per-tile
  float* red8 = (float*)(lds + 65536);                  // 8-wave nmax reduce
  STRIP_DECODE()
  const unsigned short* Yb = Y + (size_t)b * NL * ROWS_US;

  STAGE_T(At, Yb, row0)

  // per-block Nmax over nsq[b] (redundant per block; no atomics -- R8 lesson)
  float mx_ = 0.f;
  for (int i = tid; i < NL; i += 512) mx_ = fmaxf(mx_, nsq[b * NL + i]);
#pragma unroll
  for (int mk = 1; mk < 64; mk <<= 1) mx_ = fmaxf(mx_, __shfl_xor(mx_, mk));
  if (lane == 0) red8[wave] = mx_;
  __syncthreads();
  float Nmx = red8[0];
#pragma unroll
  for (int k = 1; k < 8; ++k) Nmx = fmaxf(Nmx, red8[k]);
  if (tid == 0) nmaxf[b] = Nmx;  // duplicate identical stores: benign

  float Cr[16];
#pragma unroll
  for (int rs = 0; rs < 4; ++rs)
#pragma unroll
    for (int rg = 0; rg < 4; ++rg)
      Cr[rs * 4 + rg] = sqrtf(nsq[b * NL + row0 + 64 * wr + 16 * rs + 4 * lhi + rg] * Nmx);

  float racc[16];
#pragma unroll
  for (int i = 0; i < 16; ++i) racc[i] = 0.f;

  for (int dt = 0; dt < nt; ++dt) {
    const int d = d0 + dt;
    const int col0 = ((ib + d) & 15) * 128;
    __syncthreads();  // prev Bt reads done (At stage drained at nmax barrier)
    STAGE_T(Bt, Yb, col0)
    float Cc[2];
#pragma unroll
    for (int cs = 0; cs < 2; ++cs)
      Cc[cs] = sqrtf(nsq[b * NL + col0 + 32 * wc + 16 * cs + llo] * Nmx);
    __syncthreads();  // Bt ready
    TILE_MFMA(At, Bt)
    // row-direction: csum[row0+i] partial over this wave's 32 cols
#pragma unroll
    for (int rs = 0; rs < 4; ++rs)
#pragma unroll
      for (int rg = 0; rg < 4; ++rg)
        racc[rs * 4 + rg] += EXP2(acc[rs][0][rg] - Cr[rs * 4 + rg]) +
                             EXP2(acc[rs][1][rg] - Cr[rs * 4 + rg]);
    // col-direction: per-wave partial straight to global (no LDS, no barrier)
    if (d != 0) {
      float* dst = pcs + ((size_t)(b * NSLOT + 8 + 2 * (d - 1) + wr)) * NL + col0;
#pragma unroll
      for (int cs = 0; cs < 2; ++cs) {
        float u = 0.f;
#pragma unroll
        for (int rs = 0; rs < 4; ++rs)
#pragma unroll
          for (int rg = 0; rg < 4; ++rg) u += EXP2(acc[rs][cs][rg] - Cc[cs]);
        u += __shfl_xor(u, 16);
        u += __shfl_xor(u, 32);
        if (lhi == 0) dst[32 * wc + 16 * cs + llo] = u;
      }
    }
  }
  // strip-end row-direction: llo-reduce; slot 4*hf+wc, rows disjoint by wr
#pragma unroll
  for (int i = 0; i < 16; ++i) {
    float s = racc[i];
#pragma unroll
    for (int mk = 1; mk < 16; mk <<= 1) s += __shfl_xor(s, mk);
    racc[i] = s;
  }
  if (llo == 0) {
    float* dst = pcs + ((size_t)(b * NSLOT + 4 * hf + wc)) * NL + row0;
#pragma unroll
    for (int rs = 0; rs < 4; ++rs)
#pragma unroll
      for (int rg = 0; rg < 4; ++rg)
        dst[64 * wr + 16 * rs + 4 * lhi + rg] = racc[rs * 4 + rg];
  }
}

// csum partials -> Q = -C - log2(csum)  (kept separate: fusing this unrolled
// 24-slot reduce into k_r's main loop spilled -- R18: VGPR 64, 45MB scratch)
__global__ __launch_bounds__(256) void k_comb(const float* __restrict__ pcs,
                                              const float* __restrict__ nsq,
                                              const float* __restrict__ nmaxf,
                                              float* __restrict__ Q) {
  const int i = blockIdx.x * 256 + threadIdx.x;  // b*NL + row
  const int b = i >> 11, row = i & (NL - 1);
  const int o = row >> 7;
  float s = 0.f;
#pragma unroll
  for (int c = 0; c < NSLOT; ++c) {
    if (c >= 22 && o < 8) continue;  // d=8 col-dir slots only for owners >= 8
    s += pcs[((size_t)(b * NSLOT + c)) * NL + row];
  }
  Q[i] = -sqrtf(nsq[i] * nmaxf[b]) - __log2f(s);
}

// ---- pass 2: r partials: r[l] = sum_m 2^(S' + Q_m) ----
__global__ __launch_bounds__(512, 4) void k_r(const unsigned short* __restrict__ Y,
                                              const float* __restrict__ Qa,
                                              float* __restrict__ rp) {
  __shared__ alignas(128) char lds[65536];
  unsigned short* At = (unsigned short*)lds;
  unsigned short* Bt = (unsigned short*)(lds + 32768);
  STRIP_DECODE()
  const unsigned short* Yb = Y + (size_t)b * NL * ROWS_US;

  float Qr[16];
#pragma unroll
  for (int rs = 0; rs < 4; ++rs)
#pragma unroll
    for (int rg = 0; rg < 4; ++rg)
      Qr[rs * 4 + rg] = Qa[b * NL + row0 + 64 * wr + 16 * rs + 4 * lhi + rg];

  STAGE_T(At, Yb, row0)

  float racc[16];
#pragma unroll
  for (int i = 0; i < 16; ++i) racc[i] = 0.f;

  for (int dt = 0; dt < nt; ++dt) {
    const int d = d0 + dt;
    const int col0 = ((ib + d) & 15) * 128;
    __syncthreads();
    STAGE_T(Bt, Yb, col0)
    float Qc[2];
#pragma unroll
    for (int cs = 0; cs < 2; ++cs)
      Qc[cs] = Qa[b * NL + col0 + 32 * wc + 16 * cs + llo];
    __syncthreads();
    TILE_MFMA(At, Bt)
    // row-direction: r[row0+i] += sum_m 2^(S' + Q_m) over wave's 32 cols
#pragma unroll
    for (int rs = 0; rs < 4; ++rs)
#pragma unroll
      for (int rg = 0; rg < 4; ++rg)
        racc[rs * 4 + rg] += EXP2(acc[rs][0][rg] + Qc[0]) +
                             EXP2(acc[rs][1][rg] + Qc[1]);
    // col-direction: per-wave partial straight to global
    if (d != 0) {
      float* dst = rp + ((size_t)(b * NSLOT + 8 + 2 * (d - 1) + wr)) * NL + col0;
#pragma unroll
      for (int cs = 0; cs < 2; ++cs) {
        float u = 0.f;
#pragma unroll
        for (int rs = 0; rs < 4; ++rs)
#pragma unroll
          for (int rg = 0; rg < 4; ++rg) u += EXP2(acc[rs][cs][rg] + Qr[rs * 4 + rg]);
        u += __shfl_xor(u, 16);
        u += __shfl_xor(u, 32);
        if (lhi == 0) dst[32 * wc + 16 * cs + llo] = u;
      }
    }
  }
#pragma unroll
  for (int i = 0; i < 16; ++i) {
    float s = racc[i];
#pragma unroll
    for (int mk = 1; mk < 16; mk <<= 1) s += __shfl_xor(s, mk);
    racc[i] = s;
  }
  if (llo == 0) {
    float* dst = rp + ((size_t)(b * NSLOT + 4 * hf + wc)) * NL + row0;
#pragma unroll
    for (int rs = 0; rs < 4; ++rs)
#pragma unroll
      for (int rg = 0; rg < 4; ++rg)
        dst[64 * wr + 16 * rs + 4 * lhi + rg] = racc[rs * 4 + rg];
  }
}

// ---- pass 3a: per-(b,seg) partial of sum_l w[l]*x[l,:] ----
__global__ __launch_bounds__(256) void k_outp(const float* __restrict__ x,
                                              const float* __restrict__ mask,
                                              const float* __restrict__ rp,
                                              float* __restrict__ partial) {
  const int b = blockIdx.y;
  const int seg = blockIdx.x;  // 16 segments of 128 rows; owner block == seg
  const int tid = threadIdx.x;
  const int l0 = seg * 128;
  __shared__ float w_s[128];
  __shared__ float4 red[8][32];
  if (tid < 128) {
    float s = 0.f;
#pragma unroll
    for (int c = 0; c < NSLOT; ++c) {
      if (c >= 22 && seg < 8) continue;
      s += rp[((size_t)(b * NSLOT + c)) * NL + l0 + tid];
    }
    w_s[tid] = s * mask[b * NL + l0 + tid];
  }
  __syncthreads();
  const int dq = tid & 31;
  const int rg = tid >> 5;
  float4 acc = make_float4(0.f, 0.f, 0.f, 0.f);
#pragma unroll 4
  for (int i = 0; i < 16; ++i) {
    const int l = 8 * i + rg;
    const float w = w_s[l];
    const float4 v = *reinterpret_cast<const float4*>(x + ((size_t)b * NL + l0 + l) * ND + 4 * dq);
    acc.x += w * v.x; acc.y += w * v.y; acc.z += w * v.z; acc.w += w * v.w;
  }
  red[rg][dq] = acc;
  __syncthreads();
  if (rg == 0) {
    float4 s = acc;
#pragma unroll
    for (int k = 1; k < 8; ++k) {
      const float4 t = red[k][dq];
      s.x += t.x; s.y += t.y; s.z += t.z; s.w += t.w;
    }
    *reinterpret_cast<float4*>(partial + ((size_t)(b * 16 + seg)) * ND + 4 * dq) = s;
  }
}

// ---- pass 3b: finalize out (attn_mean already filled by k_prep) ----
__global__ __launch_bounds__(1024) void k_fin(const float* __restrict__ partial,
                                              float* __restrict__ out) {
  const int gid = blockIdx.x * 1024 + threadIdx.x;  // 0..2047
  const int b = gid >> 7, d = gid & (ND - 1);
  float s = 0.f;
#pragma unroll
  for (int k = 0; k < 16; ++k) s += partial[(size_t)(b * 16 + k) * ND + d];
  out[gid] = s * (1.0f / NL);
}

extern "C" void kernel_launch(void* const* d_in, const int* in_sizes, int n_in,
                              void* d_out, int out_size, void* d_ws, size_t ws_size,
                              hipStream_t stream) {
  const float* x = (const float*)d_in[0];     // [16,2048,128] f32
  const float* mask = (const float*)d_in[1];  // [16,2048] f32
  float* out = (float*)d_out;

  unsigned short* Y = (unsigned short*)d_ws;                   // 8.4 MB
  float* nsq = (float*)(Y + (size_t)NB * NL * ROWS_US);        // [NB*NL]
  float* nmaxf = nsq + NB * NL;                                // [NB] (+pad)
  float* pcs = nmaxf + 16;                                     // [NB*NSLOT*NL]
  float* rp = pcs;                                             // alias (pcs consumed by k_comb before k_r writes rp)
  float* Q = pcs + (size_t)NB * NSLOT * NL;                    // [NB*NL]
  float* partial = Q + NB * NL;                                // [NB*16*ND]

  k_prep<<<dim3(NB * NL * ND / 4 / 256), 256, 0, stream>>>(x, mask, Y, nsq,
                                                           out + NB * ND);
  k_esum<<<dim3(512), 512, 0, stream>>>(Y, nsq, nmaxf, pcs);
  k_comb<<<dim3(NB * NL / 256), 256, 0, stream>>>(pcs, nsq, nmaxf, Q);
  k_r<<<dim3(512), 512, 0, stream>>>(Y, Q, rp);
  k_outp<<<dim3(16, NB), 256, 0, stream>>>(x, mask, rp, partial);
  k_fin<<<2, 1024, 0, stream>>>(partial, out);
}